// Round 12
// baseline (59.062 us; speedup 1.0000x reference)
//
#include <hip/hip_runtime.h>
#include <hip/hip_bf16.h>
#include <math.h>

#define NB 32
#define NS 4096
#define ND 160
#define ND4 40              // ND in float4
#define NM 16
#define NR 16
#define TPB 64              // tokens per block (16 per wave, 1 MFMA set)
#define NCB (NS / TPB)      // 64 chunks per batch

typedef float  f32x4  __attribute__((ext_vector_type(4)));
typedef short  bf16x8 __attribute__((ext_vector_type(8)));
typedef unsigned int u32x4 __attribute__((ext_vector_type(4)));

// RNE f32 -> bf16, packed pair (lo in low 16, hi in high 16)
__device__ __forceinline__ unsigned bfpair(float lo, float hi) {
    union { float f; unsigned u; } a, c;
    a.f = lo; c.f = hi;
    unsigned ua = (a.u + 0x7FFFu + ((a.u >> 16) & 1u)) >> 16;
    unsigned uc = (c.u + 0x7FFFu + ((c.u >> 16) & 1u)) >> 16;
    return (uc << 16) | (ua & 0xFFFFu);
}

__device__ __forceinline__ bf16x8 asfrag(u32x4 u) {
    union { u32x4 u; bf16x8 h; } x; x.u = u; return x.h;
}

__device__ __forceinline__ bf16x8 mkfrag(unsigned w0, unsigned w1,
                                         unsigned w2, unsigned w3) {
    union { u32x4 u; bf16x8 h; } x;
    x.u = (u32x4){w0, w1, w2, w3};
    return x.h;
}

// ---------------------------------------------------------------------------
// Kernel 0: fold K'/V per batch and emit bf16 MFMA FRAGMENTS directly.
//   K'[m][d] = 0.25*sum_r mem16[m][r]*Wrk[r][d]
//   V [m][d] =      sum_r mem16[m][r]*Wrv[d][r]
// kvfrag[b][0..319]  = kf frags: i=(kb<<6)|lane; lane=(lg<<4)|lr holds
//                      K'[lr][kb*32+lg*8 .. +7] as 4 bf16-pairs
// kvfrag[b][320..639]= vf frags: i=(d<<5)|lane32; lane32=(lg<<4)|lr holds
//                      V[lg*8+j][d*16+lr], j=0..7
// 10 KB per batch -> L2-resident for the read kernel.
// grid = NB, block = 256
// ---------------------------------------------------------------------------
__global__ __launch_bounds__(256) void ulm_fold_kv(
    const float* __restrict__ memory,
    const float* __restrict__ Wrk,     // [NR][ND]
    const float* __restrict__ Wrv,     // [ND][NR]
    u32x4* __restrict__ kvfrag)        // [NB][640]
{
    __shared__ __align__(16) float sKV[2 * NM * ND];
    __shared__ float sM16[NM * NR];
    const int b = blockIdx.x;
    const int t = threadIdx.x;

    sM16[t] = memory[((size_t)b * NM + (t >> 4)) * ND + (t & 15)];
    __syncthreads();

    if (t < ND) {
        float wk[NR], wv[NR];
#pragma unroll
        for (int r = 0; r < NR; ++r) wk[r] = Wrk[r * ND + t];
        const float4* wrv4 = reinterpret_cast<const float4*>(Wrv + t * NR);
#pragma unroll
        for (int j = 0; j < 4; ++j) {
            float4 v = wrv4[j];
            wv[j * 4 + 0] = v.x; wv[j * 4 + 1] = v.y;
            wv[j * 4 + 2] = v.z; wv[j * 4 + 3] = v.w;
        }
#pragma unroll
        for (int m = 0; m < NM; ++m) {
            float aK = 0.f, aV = 0.f;
#pragma unroll
            for (int r = 0; r < NR; ++r) {
                float mv = sM16[m * NR + r];
                aK += mv * wk[r];
                aV += mv * wv[r];
            }
            sKV[m * ND + t]           = aK * 0.25f;   // fold 1/sqrt(R)
            sKV[NM * ND + m * ND + t] = aV;
        }
    }
    __syncthreads();

    u32x4* kb4 = kvfrag + (size_t)b * 640;
    // kf fragments
    for (int i = t; i < 320; i += 256) {
        int kb = i >> 6, l = i & 63, lr = l & 15, lg = l >> 4;
        const float* s = &sKV[lr * ND + kb * 32 + lg * 8];
        kb4[i] = (u32x4){bfpair(s[0], s[1]), bfpair(s[2], s[3]),
                         bfpair(s[4], s[5]), bfpair(s[6], s[7])};
    }
    // vf fragments
    for (int i = t; i < 320; i += 256) {
        int d = i >> 5, l = i & 31, lr = l & 15, lg = l >> 4;
        const float* s = &sKV[NM * ND + (lg * 8) * ND + d * 16 + lr];
        kb4[320 + i] = (u32x4){bfpair(s[0 * ND], s[1 * ND]),
                               bfpair(s[2 * ND], s[3 * ND]),
                               bfpair(s[4 * ND], s[5 * ND]),
                               bfpair(s[6 * ND], s[7 * ND])};
    }
}

// ---------------------------------------------------------------------------
// Kernel 1: MFMA read path, pure streaming. No fold, no K/V LDS, no block
// barrier before the work. Per wave (straight-line, 16 tokens = 1 set):
//   burst-load q(10) + kf(5) + vf(10) from L2-hot kvfrag, iface(10)
//   S^T = mfma(kf, Q^T); softmax in-register; P^T via 640B wave-LDS regroup;
//   C^T = mfma(vf, P^T) -> coalesced f4 stores.
// LDS = 5 KB. NO VGPR cap (R4/R6/R9 lesson).
// grid = (NCB=64, NB=32) = 2048 blocks, 256 threads.
// ---------------------------------------------------------------------------
__global__ __launch_bounds__(256) void ulm_read_kernel(
    const float* __restrict__ query,
    const float* __restrict__ iface,
    const u32x4* __restrict__ kvfrag,  // [NB][640]
    float* __restrict__ read_out,      // [NB][NS][ND]
    float* __restrict__ ipart)         // [NB][NCB][ND]
{
    __shared__ unsigned sP[4][16 * 10];   // P^T bf16 pairs, per wave (2.5 KB)
    __shared__ float4 sIred[4 * ND4];     // 2.5 KB

    const int t = threadIdx.x;
    const int chunk = blockIdx.x;
    const int b = blockIdx.y;
    const int s0 = chunk * TPB;
    const int w  = t >> 6;             // wave 0..3
    const int l  = t & 63;
    const int lr = l & 15;             // MFMA row/col lane id
    const int lg = l >> 4;             // k-group 0..3

    const size_t base = (size_t)b * NS * ND;
    const int tok = s0 + w * 16 + lr;

    // --- burst 1: q loads (10 float4) ---------------------------------------
    const float4* q4 = reinterpret_cast<const float4*>(query + base);
    float4 qr[10];
#pragma unroll
    for (int kb = 0; kb < 5; ++kb) {
        qr[2*kb]   = q4[(size_t)tok * ND4 + lg * 2 + kb * 8];
        qr[2*kb+1] = q4[(size_t)tok * ND4 + lg * 2 + kb * 8 + 1];
    }

    // --- burst 2: K'/V fragments from L2-hot kvfrag (15 loads) -------------
    const u32x4* kvb = kvfrag + (size_t)b * 640;
    u32x4 kfu[5];
#pragma unroll
    for (int kb = 0; kb < 5; ++kb) kfu[kb] = kvb[kb * 64 + l];
    u32x4 vfu[10];
#pragma unroll
    for (int d = 0; d < 10; ++d)
        vfu[d] = (lg < 2) ? kvb[320 + d * 32 + (l & 31)]
                          : (u32x4){0u, 0u, 0u, 0u};

    // --- S^T = sum_kb mfma(kf[kb], qf[kb]) : D[m=lg*4+r][tok=lr] -----------
    f32x4 D = {0.f, 0.f, 0.f, 0.f};
#pragma unroll
    for (int kb = 0; kb < 5; ++kb) {
        bf16x8 qf = mkfrag(bfpair(qr[2*kb].x,   qr[2*kb].y),
                           bfpair(qr[2*kb].z,   qr[2*kb].w),
                           bfpair(qr[2*kb+1].x, qr[2*kb+1].y),
                           bfpair(qr[2*kb+1].z, qr[2*kb+1].w));
        D = __builtin_amdgcn_mfma_f32_16x16x32_bf16(asfrag(kfu[kb]), qf, D, 0, 0, 0);
    }

    // --- softmax over m: in-lane 4 + cross-group xor16, xor32 --------------
    float mx = fmaxf(fmaxf(D[0], D[1]), fmaxf(D[2], D[3]));
    mx = fmaxf(mx, __shfl_xor(mx, 16));
    mx = fmaxf(mx, __shfl_xor(mx, 32));
    float e0 = __expf(D[0] - mx), e1 = __expf(D[1] - mx);
    float e2 = __expf(D[2] - mx), e3 = __expf(D[3] - mx);
    float sm = e0 + e1 + e2 + e3;
    sm += __shfl_xor(sm, 16);
    sm += __shfl_xor(sm, 32);
    float inv = 1.f / sm;
    e0 *= inv; e1 *= inv; e2 *= inv; e3 *= inv;

    // --- P^T regroup via wave-private LDS ----------------------------------
    unsigned* pl = &sP[w][0];
    pl[lr * 10 + lg * 2 + 0] = bfpair(e0, e1);
    pl[lr * 10 + lg * 2 + 1] = bfpair(e2, e3);
    asm volatile("s_waitcnt lgkmcnt(0)" ::: "memory");
    int pb = (lg < 2) ? (lr * 10 + lg * 4) : 0;
    bf16x8 pf = mkfrag(pl[pb], pl[pb + 1], pl[pb + 2], pl[pb + 3]);

    // --- burst 3: iface loads (consumed after PV; PV hides their latency) --
    const float4* i4 = reinterpret_cast<const float4*>(iface + base);
    const int l8 = l & 7, g8 = l >> 3;
    const int itok = s0 + w * 16 + g8 * 2;
    float4 iv[10];
#pragma unroll
    for (int j = 0; j < 2; ++j)
#pragma unroll
        for (int k = 0; k < 5; ++k)
            iv[j * 5 + k] = i4[(size_t)(itok + j) * ND4 + l8 + 8 * k];

    // --- C^T = mfma(vf[d], pf): D2[dcol=d*16+lg*4+r][tok=lr] -> f4 stores ---
    float4* out4 = reinterpret_cast<float4*>(read_out + base);
#pragma unroll
    for (int d = 0; d < 10; ++d) {
        f32x4 D2 = {0.f, 0.f, 0.f, 0.f};
        D2 = __builtin_amdgcn_mfma_f32_16x16x32_bf16(asfrag(vfu[d]), pf, D2, 0, 0, 0);
        out4[(size_t)tok * ND4 + d * 4 + lg] = make_float4(D2[0], D2[1], D2[2], D2[3]);
    }

    // --- iface butterfly: sum this wave's 16 token-rows --------------------
#pragma unroll
    for (int k = 0; k < 5; ++k) {
        float x = iv[k].x + iv[5 + k].x, y = iv[k].y + iv[5 + k].y;
        float z = iv[k].z + iv[5 + k].z, u = iv[k].w + iv[5 + k].w;
#pragma unroll
        for (int off = 8; off <= 32; off <<= 1) {
            x += __shfl_xor(x, off); y += __shfl_xor(y, off);
            z += __shfl_xor(z, off); u += __shfl_xor(u, off);
        }
        if (l < 8) sIred[w * ND4 + k * 8 + l8] = make_float4(x, y, z, u);
    }
    __syncthreads();
    if (t < ND4) {
        float4 a0 = sIred[t], a1 = sIred[ND4 + t];
        float4 a2 = sIred[2 * ND4 + t], a3 = sIred[3 * ND4 + t];
        float4 tot = make_float4(a0.x + a1.x + a2.x + a3.x,
                                 a0.y + a1.y + a2.y + a3.y,
                                 a0.z + a1.z + a2.z + a3.z,
                                 a0.w + a1.w + a2.w + a3.w);
        reinterpret_cast<float4*>(ipart + ((size_t)(b * NCB + chunk)) * ND)[t] = tot;
    }
}

// ---------------------------------------------------------------------------
// Kernel 2: write path. i_mean -> i_proj -> erase/add -> layer_norm(new_mem)
// grid = NB, block = 256
// ---------------------------------------------------------------------------
__global__ __launch_bounds__(256) void ulm_write_kernel(
    const float* __restrict__ memory,
    const float* __restrict__ Wwk,     // [NR][ND]
    const float* __restrict__ Wwe,     // [ND][NR]
    const float* __restrict__ Wwa,     // [ND][NR]
    const float* __restrict__ ipart,   // [NB][NCB][ND]
    float* __restrict__ new_mem)       // [NB][NM][ND]
{
    __shared__ float sIm[ND];
    __shared__ float sIp[NR];
    __shared__ float sOmE[ND];   // 1 - erase
    __shared__ float sAdd[ND];

    const int b = blockIdx.x;
    const int t = threadIdx.x;

    if (t < ND) {
        float acc = 0.f;
#pragma unroll 8
        for (int c = 0; c < NCB; ++c)
            acc += ipart[((size_t)(b * NCB + c)) * ND + t];
        sIm[t] = acc * (1.0f / NS);
    }
    __syncthreads();

    if (t < NR) {
        float acc = 0.f;
        for (int d = 0; d < ND; ++d) acc += sIm[d] * Wwk[t * ND + d];
        sIp[t] = acc;
    }
    __syncthreads();

    if (t < ND) {
        float e = 0.f, a = 0.f;
#pragma unroll
        for (int r = 0; r < NR; ++r) {
            float ip = sIp[r];
            e += ip * Wwe[t * NR + r];
            a += ip * Wwa[t * NR + r];
        }
        sOmE[t] = 1.0f - 1.0f / (1.0f + __expf(-e));
        sAdd[t] = a;
    }
    __syncthreads();

    // layer norm each of the 16 memory rows; one wave per row
    const int wave = t >> 6, lane = t & 63;
    for (int m = wave; m < NM; m += 4) {
        const float* mrow = memory + ((size_t)b * NM + m) * ND;
        float v0 = mrow[lane] * sOmE[lane] + sAdd[lane];
        float v1 = mrow[lane + 64] * sOmE[lane + 64] + sAdd[lane + 64];
        float v2 = 0.f;
        const bool has2 = lane < 32;
        if (has2) v2 = mrow[lane + 128] * sOmE[lane + 128] + sAdd[lane + 128];
        float s  = v0 + v1 + v2;
        float sq = v0 * v0 + v1 * v1 + v2 * v2;
#pragma unroll
        for (int off = 32; off; off >>= 1) {
            s  += __shfl_xor(s, off);
            sq += __shfl_xor(sq, off);
        }
        float mu   = s * (1.0f / ND);
        float var  = sq * (1.0f / ND) - mu * mu;
        float rstd = rsqrtf(var + 1e-5f);
        float* orow = new_mem + ((size_t)b * NM + m) * ND;
        orow[lane]      = (v0 - mu) * rstd;
        orow[lane + 64] = (v1 - mu) * rstd;
        if (has2) orow[lane + 128] = (v2 - mu) * rstd;
    }
}

extern "C" void kernel_launch(void* const* d_in, const int* in_sizes, int n_in,
                              void* d_out, int out_size, void* d_ws, size_t ws_size,
                              hipStream_t stream) {
    const float* query  = (const float*)d_in[0];
    const float* iface  = (const float*)d_in[1];
    const float* memory = (const float*)d_in[2];
    const float* Wrk    = (const float*)d_in[3];
    const float* Wrv    = (const float*)d_in[4];
    const float* Wwk    = (const float*)d_in[5];
    const float* Wwe    = (const float*)d_in[6];
    const float* Wwa    = (const float*)d_in[7];

    float* read_out = (float*)d_out;                        // [32][4096][160]
    float* new_mem  = (float*)d_out + (size_t)NB * NS * ND; // [32][16][160]
    float* ipart    = (float*)d_ws;                         // NB*NCB*ND f32 = 1.31 MB
    u32x4* kvfrag   = (u32x4*)((float*)d_ws + (size_t)NB * NCB * ND); // 327 KB

    ulm_fold_kv<<<NB, 256, 0, stream>>>(memory, Wrk, Wrv, kvfrag);
    dim3 grid1(NCB, NB);
    ulm_read_kernel<<<grid1, 256, 0, stream>>>(query, iface, kvfrag,
                                               read_out, ipart);
    ulm_write_kernel<<<NB, 256, 0, stream>>>(memory, Wwk, Wwe, Wwa, ipart, new_mem);
}